// Round 9
// baseline (507.556 us; speedup 1.0000x reference)
//
#include <hip/hip_runtime.h>
#include <hip/hip_bf16.h>
#include <stdint.h>

// GAT-style attention layer, B=4 N=4096 Din=256 Dout=128, fp32 in/out.
// Pipeline:
//  k1 : h = x@W (fp32), store hT (fp16, [b][d][n]) + Wh1/Wh2 = h@a (fp32)
//  k2 : ONE coalesced pass over adj: S_j (atomicAdd) + transposed bitmask
//  k25: Sinv = 1/S
//  k3 : out = gelu(P @ h), fp16 MFMA; B-fragments loaded DIRECTLY from global
//       into VGPRs (16 B contiguous per lane) — no LDS in the K-loop.
//       R8 lesson: the DMA->LDS path had an unswizzlable 8-way bank conflict
//       (DMA's lane*16B layout forces 64 B row stride; quad offset = 256 B ==
//       0 mod 32 banks) + per-chunk vmcnt(0)/lgkm drains. Wave-private
//       B-slices mean LDS bought nothing.
//  k4b: L2-normalize over i + bias

#define NN   4096
#define BB   4
#define DIN  256
#define DOUT 128

typedef unsigned short u16;
typedef _Float16 f16x8 __attribute__((ext_vector_type(8)));
typedef __attribute__((ext_vector_type(4))) float f32x4;

__device__ __forceinline__ u16 f2h_bits(float f) {
  _Float16 h = (_Float16)f;          // v_cvt_f16_f32, RNE
  union { _Float16 h; u16 u; } v; v.h = h;
  return v.u;
}

// Abramowitz-Stegun 7.1.26, |err| < 1.5e-7
__device__ __forceinline__ float erf_f(float x) {
  float ax = __builtin_fabsf(x);
  float t  = __builtin_amdgcn_rcpf(__builtin_fmaf(0.3275911f, ax, 1.0f));
  float p  = __builtin_fmaf(1.061405429f, t, -1.453152027f);
  p = __builtin_fmaf(p, t, 1.421413741f);
  p = __builtin_fmaf(p, t, -0.284496736f);
  p = __builtin_fmaf(p, t, 0.254829592f);
  p = p * t;
  float e  = __expf(-ax * ax);
  float er = __builtin_fmaf(-p, e, 1.0f);
  return copysignf(er, x);
}

__device__ __forceinline__ float gelu_f(float z) {
  float hz = 0.5f * z;
  return __builtin_fmaf(hz, erf_f(z * 0.70710678118654752f), hz);
}

__device__ __forceinline__ float exp_gelu(float z) { return __expf(gelu_f(z)); }

// ---------------- k1: h = x@W, Wh1/Wh2, hT(fp16) ----------------
__global__ __launch_bounds__(256, 2) void k1_proj(
    const float* __restrict__ x, const float* __restrict__ weight,
    const float* __restrict__ a, u16* __restrict__ hT,
    float* __restrict__ Wh1, float* __restrict__ Wh2)
{
  __shared__ float xs[32 * 256];     // 32 KB
  __shared__ float T[128 * 33];      // padded transpose buffer (16.9 KB)
  __shared__ float P2a[8 * 32], P2b[8 * 32];

  const int b = blockIdx.y, n0 = blockIdx.x * 32;
  const int tid = threadIdx.x;

  const float4* xsrc = (const float4*)(x + ((size_t)b * NN + n0) * DIN);
  float4* xd = (float4*)xs;
#pragma unroll
  for (int v = 0; v < 8; ++v) xd[tid + v * 256] = xsrc[tid + v * 256];
  __syncthreads();

  const int dg = tid & 31, rg = tid >> 5;
  float acc[4][4] = {};
  const float4* W4 = (const float4*)weight;
#pragma unroll 4
  for (int k = 0; k < 256; ++k) {
    float4 wr = W4[k * 32 + dg];
#pragma unroll
    for (int rr = 0; rr < 4; ++rr) {
      float xv = xs[(rg * 4 + rr) * 256 + k];
      acc[rr][0] = fmaf(xv, wr.x, acc[rr][0]);
      acc[rr][1] = fmaf(xv, wr.y, acc[rr][1]);
      acc[rr][2] = fmaf(xv, wr.z, acc[rr][2]);
      acc[rr][3] = fmaf(xv, wr.w, acc[rr][3]);
    }
  }
#pragma unroll
  for (int rr = 0; rr < 4; ++rr)
#pragma unroll
    for (int dd = 0; dd < 4; ++dd)
      T[(dg * 4 + dd) * 33 + rg * 4 + rr] = acc[rr][dd];
  __syncthreads();

  {
    const int d = tid & 127, half = tid >> 7;
    unsigned int uu[8];
#pragma unroll
    for (int p = 0; p < 8; ++p) {
      float f0 = T[d * 33 + half * 16 + p * 2];
      float f1 = T[d * 33 + half * 16 + p * 2 + 1];
      uu[p] = (unsigned int)f2h_bits(f0) | ((unsigned int)f2h_bits(f1) << 16);
    }
    u16* dst = hT + ((size_t)b * DOUT + d) * NN + n0 + half * 16;
    ((uint4*)dst)[0] = make_uint4(uu[0], uu[1], uu[2], uu[3]);
    ((uint4*)dst)[1] = make_uint4(uu[4], uu[5], uu[6], uu[7]);
  }
  {
    const int r = tid & 31, g8 = tid >> 5;
    float p1 = 0.f, p2 = 0.f;
#pragma unroll
    for (int q = 0; q < 16; ++q) {
      int d = g8 * 16 + q;
      float hv = T[d * 33 + r];
      p1 = fmaf(hv, a[d], p1);
      p2 = fmaf(hv, a[DOUT + d], p2);
    }
    P2a[g8 * 32 + r] = p1;
    P2b[g8 * 32 + r] = p2;
  }
  __syncthreads();
  if (tid < 32) {
    float s1 = 0.f, s2 = 0.f;
#pragma unroll
    for (int g8 = 0; g8 < 8; ++g8) { s1 += P2a[g8 * 32 + tid]; s2 += P2b[g8 * 32 + tid]; }
    Wh1[b * NN + n0 + tid] = s1;
    Wh2[b * NN + n0 + tid] = s2;
  }
}

// ---------------- k2: fused adj pass -> S_j + transposed bitmask ----------------
__global__ __launch_bounds__(256) void k2_fused(
    const int* __restrict__ adj, const float* __restrict__ Wh1,
    const float* __restrict__ Wh2, float* __restrict__ S,
    unsigned int* __restrict__ m32)
{
  const int b = blockIdx.z, jt = blockIdx.x, ic = blockIdx.y;
  const int tid = threadIdx.x;
  const int j = jt * 256 + tid;
  const int lane = tid & 63;
  const int jg = jt * 4 + (tid >> 6);      // global 64-j group
  const int i0 = ic * 128;

  const float wh2 = Wh2[b * NN + j];
  const int* ap = adj + ((size_t)b * NN + i0) * NN + j;
  const float* w1p = Wh1 + b * NN + i0;
  unsigned int* mlo = m32 + ((size_t)b * 128 + jg * 2) * NN + i0;
  unsigned int* mhi = mlo + NN;

  float s = 0.f;
  for (int g = 0; g < 2; ++g) {            // 2 groups of 64 rows
    unsigned long long acc64 = 0ull;
#pragma unroll
    for (int gg = 0; gg < 4; ++gg) {       // 4 sub-batches of 16 rows
      int av[16]; float w1v[16];
#pragma unroll
      for (int k = 0; k < 16; ++k) {
        const int ii = g * 64 + gg * 16 + k;
        av[k]  = ap[(size_t)ii * NN];
        w1v[k] = w1p[ii];                  // block-uniform -> scalar load
      }
#pragma unroll
      for (int k = 0; k < 16; ++k) {
        const unsigned long long bal = __ballot(av[k] > 0);
        if (lane == gg * 16 + k) acc64 = bal;   // cndmask keep
        const float E = exp_gelu(w1v[k] + wh2);
        s += (av[k] > 0) ? E : 0.f;
      }
    }
    mlo[g * 64 + lane] = (unsigned int)acc64;          // coalesced 256 B
    mhi[g * 64 + lane] = (unsigned int)(acc64 >> 32);  // coalesced 256 B
  }
  atomicAdd(&S[b * NN + j], s);
}

__global__ __launch_bounds__(256) void k25_rcp(const float* __restrict__ S,
                                               float* __restrict__ Sinv)
{
  int id = blockIdx.x * 256 + threadIdx.x;
  Sinv[id] = 1.0f / S[id];     // all-masked column cannot occur (p=0.5, N=4096)
}

// ---------------- k3: out = gelu(P @ h), fp16 MFMA, no K-loop LDS ----------------
// grid (NN/32, BB) = 512 blocks, block 256 = 4 waves; block covers 32 rows.
// Wave w owns j in [w*1024, +1024) (4-way K-split). B-fragment for lane
// (m,quad), d-tile t: hT[t*16+m][j0+quad*8 .. +7] = 16 contiguous bytes ->
// direct global_load_dwordx4 into VGPRs. Load latency hides behind the
// ~800-cycle A-generation (16 exp_gelu) preceding the MFMAs each chunk.
// Epilogue: K-split reduce in LDS, gelu, write d_out, norm2 atomics.
__global__ __launch_bounds__(256, 2) void k3_attn(
    const unsigned int* __restrict__ m32, const float* __restrict__ Wh1,
    const float* __restrict__ Wh2, const float* __restrict__ Sinv,
    const u16* __restrict__ hT, float* __restrict__ out,
    float* __restrict__ norm2)
{
  __shared__ float red[4 * 2048];    // 32 KB epilogue scratch

  const int b = blockIdx.y;
  const int i0 = blockIdx.x * 32;
  const int tid = threadIdx.x;
  const int w = tid >> 6, lane = tid & 63;
  const int m = lane & 15, quad = lane >> 4;

  const float w1a = Wh1[b * NN + i0 + m];
  const float w1b = Wh1[b * NN + i0 + 16 + m];
  const unsigned int* mbase = m32 + (size_t)b * 128 * NN;
  const u16* hTb = hT + (size_t)b * DOUT * NN;
  // per-lane B base: row m, j-offset quad*8 (16-B aligned)
  const u16* bsrc = hTb + (size_t)m * NN + quad * 8;

  f32x4 acc0[8], acc1[8];
#pragma unroll
  for (int t = 0; t < 8; ++t) {
    acc0[t] = (f32x4){0.f, 0.f, 0.f, 0.f};
    acc1[t] = (f32x4){0.f, 0.f, 0.f, 0.f};
  }

  for (int c = 0; c < 32; ++c) {
    const int j0 = w * 1024 + c * 32;
    const int jw = j0 >> 5;

    // B-fragments: 8 independent 16-B loads (issued before the VALU block)
    f16x8 bf[8];
#pragma unroll
    for (int t = 0; t < 8; ++t)
      bf[t] = *(const f16x8*)(bsrc + (size_t)t * 16 * NN + j0);

    // masks for both row-tiles (transposed planes, coalesced over m)
    const unsigned int Ma = mbase[(size_t)jw * NN + i0 + m];
    const unsigned int Mb = mbase[(size_t)jw * NN + i0 + 16 + m];
    const unsigned int mba = (Ma >> (quad * 8)) & 0xFFu;
    const unsigned int mbb = (Mb >> (quad * 8)) & 0xFFu;

    const int jq = j0 + quad * 8;
    const float4* wp = (const float4*)(Wh2 + b * NN + jq);
    float4 w2a = wp[0], w2b = wp[1];
    const float4* sp = (const float4*)(Sinv + b * NN + jq);
    float4 sva = sp[0], svb = sp[1];

    f16x8 ah_a, ah_b;
    // row-tile a (rows i0..i0+15)
    ah_a[0] = (_Float16)((mba & 1u)   ? exp_gelu(w1a + w2a.x) * sva.x : 0.f);
    ah_a[1] = (_Float16)((mba & 2u)   ? exp_gelu(w1a + w2a.y) * sva.y : 0.f);
    ah_a[2] = (_Float16)((mba & 4u)   ? exp_gelu(w1a + w2a.z) * sva.z : 0.f);
    ah_a[3] = (_Float16)((mba & 8u)   ? exp_gelu(w1a + w2a.w) * sva.w : 0.f);
    ah_a[4] = (_Float16)((mba & 16u)  ? exp_gelu(w1a + w2b.x) * svb.x : 0.f);
    ah_a[5] = (_Float16)((mba & 32u)  ? exp_gelu(w1a + w2b.y) * svb.y : 0.f);
    ah_a[6] = (_Float16)((mba & 64u)  ? exp_gelu(w1a + w2b.z) * svb.z : 0.f);
    ah_a[7] = (_Float16)((mba & 128u) ? exp_gelu(w1a + w2b.w) * svb.w : 0.f);
    // row-tile b (rows i0+16..i0+31)
    ah_b[0] = (_Float16)((mbb & 1u)   ? exp_gelu(w1b + w2a.x) * sva.x : 0.f);
    ah_b[1] = (_Float16)((mbb & 2u)   ? exp_gelu(w1b + w2a.y) * sva.y : 0.f);
    ah_b[2] = (_Float16)((mbb & 4u)   ? exp_gelu(w1b + w2a.z) * sva.z : 0.f);
    ah_b[3] = (_Float16)((mbb & 8u)   ? exp_gelu(w1b + w2a.w) * sva.w : 0.f);
    ah_b[4] = (_Float16)((mbb & 16u)  ? exp_gelu(w1b + w2b.x) * svb.x : 0.f);
    ah_b[5] = (_Float16)((mbb & 32u)  ? exp_gelu(w1b + w2b.y) * svb.y : 0.f);
    ah_b[6] = (_Float16)((mbb & 64u)  ? exp_gelu(w1b + w2b.z) * svb.z : 0.f);
    ah_b[7] = (_Float16)((mbb & 128u) ? exp_gelu(w1b + w2b.w) * svb.w : 0.f);

#pragma unroll
    for (int t = 0; t < 8; ++t) {
      acc0[t] = __builtin_amdgcn_mfma_f32_16x16x32_f16(ah_a, bf[t], acc0[t], 0, 0, 0);
      acc1[t] = __builtin_amdgcn_mfma_f32_16x16x32_f16(ah_b, bf[t], acc1[t], 0, 0, 0);
    }
  }

  // 4-way K-split reduce (red = 4 x 2048 fp32 = 32 KB), two passes.
  // Fused epilogue: gelu -> out, accumulate per-d sum of squares.
  float p2[2] = {0.f, 0.f};
#pragma unroll
  for (int rt = 0; rt < 2; ++rt) {
    __syncthreads();
#pragma unroll
    for (int t = 0; t < 8; ++t)
#pragma unroll
      for (int r = 0; r < 4; ++r)
        red[w * 2048 + (t * 4 + r) * 64 + lane] = rt ? acc1[t][r] : acc0[t][r];
    __syncthreads();
    // wave w finalizes d-tiles t = 2w, 2w+1 (C layout: row=quad*4+r, col=t*16+m)
#pragma unroll
    for (int tt = 0; tt < 2; ++tt) {
      const int t = w * 2 + tt;
#pragma unroll
      for (int r = 0; r < 4; ++r) {
        const int o = (t * 4 + r) * 64 + lane;
        float v = red[o] + red[2048 + o] + red[4096 + o] + red[6144 + o];
        float gv = gelu_f(v);
        out[((size_t)b * NN + i0 + rt * 16 + quad * 4 + r) * DOUT + t * 16 + m] = gv;
        p2[tt] = fmaf(gv, gv, p2[tt]);
      }
    }
  }
  // cross-quad reduce (lanes m, m+16, m+32, m+48 share d), one atomic per d
#pragma unroll
  for (int tt = 0; tt < 2; ++tt) {
    float ps = p2[tt];
    ps += __shfl_xor(ps, 16);
    ps += __shfl_xor(ps, 32);
    if (quad == 0)
      atomicAdd(&norm2[b * DOUT + (w * 2 + tt) * 16 + m], ps);
  }
}

// ---------------- k4b: scale by 1/max(||col||,1e-12) + bias ----------------
__global__ __launch_bounds__(256) void k4b_scale(
    float* __restrict__ out, const float* __restrict__ norm2,
    const float* __restrict__ bias)
{
  int id = blockIdx.x * 256 + threadIdx.x;
  int d = id & 127;
  int b = id >> 19;                        // N*DOUT = 2^19 per batch
  float nrm = sqrtf(norm2[b * DOUT + d]);
  float sc = 1.0f / fmaxf(nrm, 1e-12f);
  out[id] = fmaf(out[id], sc, bias[d]);
}

extern "C" void kernel_launch(void* const* d_in, const int* in_sizes, int n_in,
                              void* d_out, int out_size, void* d_ws, size_t ws_size,
                              hipStream_t stream)
{
  const float* x      = (const float*)d_in[0];
  const int*   adj    = (const int*)d_in[1];
  const float* weight = (const float*)d_in[2];
  const float* a      = (const float*)d_in[3];
  const float* bias   = (const float*)d_in[4];
  float* out = (float*)d_out;

  // workspace layout (all 16B aligned), ~12.3 MB total
  char* ws = (char*)d_ws;
  u16*   hT     = (u16*)ws;                                    // 4 MB
  float* Wh1    = (float*)(ws + (size_t)4 * 1024 * 1024);      // 64 KB
  float* Wh2    = Wh1 + BB * NN;                               // 64 KB
  float* S      = Wh2 + BB * NN;                               // 64 KB
  float* Sinv   = S + BB * NN;                                 // 64 KB
  unsigned int* m32 = (unsigned int*)(Sinv + BB * NN);         // 8 MB, [b][128][4096]
  float* norm2  = (float*)((char*)m32 + (size_t)BB * 128 * NN * 4);  // 2 KB

  hipMemsetAsync(S, 0, (size_t)BB * NN * sizeof(float), stream);
  hipMemsetAsync(norm2, 0, (size_t)BB * DOUT * sizeof(float), stream);

  k1_proj<<<dim3(NN / 32, BB), 256, 0, stream>>>(x, weight, a, hT, Wh1, Wh2);
  k2_fused<<<dim3(16, 32, BB), 256, 0, stream>>>(adj, Wh1, Wh2, S, m32);
  k25_rcp<<<dim3(BB * NN / 256), 256, 0, stream>>>(S, Sinv);
  k3_attn<<<dim3(NN / 32, BB), 256, 0, stream>>>(m32, Wh1, Wh2, Sinv, hT, out, norm2);
  k4b_scale<<<dim3((BB * NN * DOUT) / 256), 256, 0, stream>>>(out, norm2, bias);
}